// Round 6
// baseline (1735.467 us; speedup 1.0000x reference)
//
#include <hip/hip_runtime.h>
#include <math.h>

// Problem constants
#define BB   4
#define LL   4096
#define DIMC 2048
#define SC   128
#define MM   (BB*LL)        // 16384 rows
#define NC   256            // scan chunks per sequence
#define LCH  (LL/NC)        // 16 = chunk length

typedef __attribute__((ext_vector_type(8))) short bf16x8;
typedef __attribute__((ext_vector_type(4))) float f32x4;

#define MFMA(a,b,c) __builtin_amdgcn_mfma_f32_16x16x32_bf16(a,b,c,0,0,0)

// RNE float -> bf16 bits
__device__ inline unsigned short bf16h(float v) {
    unsigned u = __float_as_uint(v);
    return (unsigned short)((u + 0x7FFFu + ((u >> 16) & 1u)) >> 16);
}
__device__ inline float bf2f(unsigned short h) {
    return __uint_as_float(((unsigned)h) << 16);
}

// ---------------------------------------------------------------------------
// Kernel 0: build fragment-linear bf16 hi/lo weights.
// MFMA 16x16x32 fragment: slot = (ktile*NF + nfrag)*64 + lane, 8 bf16/slot:
// element j = W[k = ktile*32 + 8*(lane>>4) + j][n = nfrag*16 + (lane&15)].
// W1 (K=4096, N=384): n 0..127 dt ([xr;xi] @ dt_w rows), 128..255 Bx_re
// ([Br;-Bi]), 256..383 Bx_im ([Bi;Br]).  W2 (K=2048, N=128): pg_w^T.
// W3 (K=256, N=4096): n = d*2+comp; comp0 (yr): [Cr;-Ci], comp1 (yi): [Ci;Cr].
// ---------------------------------------------------------------------------
#define W1_SLOTS (128*24)
#define W2_SLOTS (64*8)
#define W3_SLOTS (8*256)
__global__ void prep_w(const float* __restrict__ dt_w,
                       const float* __restrict__ Br,
                       const float* __restrict__ Bi,
                       const float* __restrict__ pg_w,
                       const float* __restrict__ Cr,
                       const float* __restrict__ Ci,
                       short* __restrict__ W1h, short* __restrict__ W1l,
                       short* __restrict__ W2h, short* __restrict__ W2l,
                       short* __restrict__ W3h, short* __restrict__ W3l) {
    int id = threadIdx.x + blockIdx.x * 256;
    int lane = id & 63;
    int slot = id >> 6;
    float v[8];
    short* dsth; short* dstl;
    if (slot < W1_SLOTS) {
        int kt = slot / 24, nf = slot % 24;
        int n  = nf * 16 + (lane & 15);
        int k0 = kt * 32 + 8 * (lane >> 4);
        if (n < 128) {
            const float* p = dt_w + (size_t)n * 4096 + k0;
            #pragma unroll
            for (int j = 0; j < 8; ++j) v[j] = p[j];
        } else if (n < 256) {
            int s = n - 128;
            #pragma unroll
            for (int j = 0; j < 8; ++j) {
                int k = k0 + j;
                v[j] = (k < 2048) ? Br[(size_t)k * 128 + s]
                                  : -Bi[(size_t)(k - 2048) * 128 + s];
            }
        } else {
            int s = n - 256;
            #pragma unroll
            for (int j = 0; j < 8; ++j) {
                int k = k0 + j;
                v[j] = (k < 2048) ? Bi[(size_t)k * 128 + s]
                                  : Br[(size_t)(k - 2048) * 128 + s];
            }
        }
        dsth = W1h + (size_t)id * 8; dstl = W1l + (size_t)id * 8;
    } else if (slot < W1_SLOTS + W2_SLOTS) {
        int s2 = slot - W1_SLOTS;
        int kt = s2 / 8, nf = s2 % 8;
        int s  = nf * 16 + (lane & 15);
        int k0 = kt * 32 + 8 * (lane >> 4);
        const float* p = pg_w + (size_t)s * 2048 + k0;
        #pragma unroll
        for (int j = 0; j < 8; ++j) v[j] = p[j];
        dsth = W2h + (size_t)(id - W1_SLOTS * 64) * 8;
        dstl = W2l + (size_t)(id - W1_SLOTS * 64) * 8;
    } else {
        int s3 = slot - W1_SLOTS - W2_SLOTS;
        int kt = s3 / 256, nf = s3 % 256;
        int n  = nf * 16 + (lane & 15);
        int d = n >> 1, comp = n & 1;
        int k0 = kt * 32 + 8 * (lane >> 4);
        #pragma unroll
        for (int j = 0; j < 8; ++j) {
            int k = k0 + j;
            int s = k & 127;
            float c;
            if (k < 128) c = comp ? Ci[(size_t)s * 2048 + d] : Cr[(size_t)s * 2048 + d];
            else         c = comp ? Cr[(size_t)s * 2048 + d] : -Ci[(size_t)s * 2048 + d];
            v[j] = c;
        }
        dsth = W3h + (size_t)(id - (W1_SLOTS + W2_SLOTS) * 64) * 8;
        dstl = W3l + (size_t)(id - (W1_SLOTS + W2_SLOTS) * 64) * 8;
    }
    bf16x8 hv, lv;
    #pragma unroll
    for (int j = 0; j < 8; ++j) {
        unsigned short h = bf16h(v[j]);
        hv[j] = (short)h;
        lv[j] = (short)bf16h(v[j] - bf2f(h));
    }
    *(bf16x8*)dsth = hv;
    *(bf16x8*)dstl = lv;
}

// ---------------------------------------------------------------------------
// Kernel 1: fused projections via split-bf16 MFMA (hh + hl + lh products).
// 256 blocks x 512 thr (8 waves). BM=64; waves N-split: wave w owns GEMM1
// cols [48w,48w+48) and GEMM2 col-frag w. Per 64-d block: stage xr/xi/|x|
// hi+lo fragment-linear into LDS.
// v2: LDS capped at 48 KB (epilogue = four 16-row passes through a
// [16][520] padded exchange buffer instead of one 64 KB 32x512 buffer)
// -> 3 blocks/CU via launch_bounds(512,6) (was 2 blocks, all pipes <24%).
// ---------------------------------------------------------------------------
__global__ __launch_bounds__(512, 6) void phase1(
    const float* __restrict__ x,        // (M, DIM, 2)
    const short* __restrict__ W1h, const short* __restrict__ W1l,
    const short* __restrict__ W2h, const short* __restrict__ W2l,
    const float* __restrict__ log_A_real,
    const float* __restrict__ log_A_imag,
    const float* __restrict__ dt_b,
    const float* __restrict__ dt_bias,
    const float* __restrict__ pg_b,
    float* __restrict__ ABx)            // (M,S) float4 (Ar,Ai,Bxr,Bxi)
{
    const int tid  = threadIdx.x;
    const int lane = tid & 63;
    const int wv   = tid >> 6;
    const int m0   = blockIdx.x * 64;

    // streams: 0 xr_hi, 1 xr_lo, 2 xi_hi, 3 xi_lo, 4 cb_hi, 5 cb_lo
    __shared__ __align__(16) union SmemT {
        short comp[6][2][4][64][8];   // [stream][kf][mf][lane][j]  48 KB
        float ep[16][520];            // epilogue exchange (padded) 33 KB
    } smem;

    f32x4 c1[3][4];   // [nf_local][mf]
    f32x4 c2[4];      // [mf]
    #pragma unroll
    for (int n = 0; n < 3; ++n)
        #pragma unroll
        for (int m = 0; m < 4; ++m) c1[n][m] = (f32x4){0.f,0.f,0.f,0.f};
    #pragma unroll
    for (int m = 0; m < 4; ++m) c2[m] = (f32x4){0.f,0.f,0.f,0.f};

    const float2* x2 = (const float2*)x;
    // staging persona: row = tid>>3 (0..63), 8 consecutive d per thread
    const int srow = tid >> 3;
    const int sdg  = tid & 7;          // d_local = sdg*8 + j
    const int smf  = srow >> 4;
    const int skf  = sdg >> 2;         // = d_local>>5
    const int spl  = (srow & 15) + 16 * (sdg & 3);   // lane-slot = r15 + 16*lg

    float4 q[4];
    {
        const float4* xp = (const float4*)(x2 + (size_t)(m0 + srow) * DIMC + sdg * 8);
        #pragma unroll
        for (int i = 0; i < 4; ++i) q[i] = xp[i];
    }

    for (int db = 0; db < 32; ++db) {
        __syncthreads();   // prior compute done reading lds
        {
            bf16x8 vxh, vxl, vih, vil, vch, vcl;
            #pragma unroll
            for (int j = 0; j < 8; ++j) {
                int qi = j >> 1;
                float xr = (j & 1) ? q[qi].z : q[qi].x;
                float xi = (j & 1) ? q[qi].w : q[qi].y;
                unsigned short h1 = bf16h(xr);
                vxh[j] = (short)h1; vxl[j] = (short)bf16h(xr - bf2f(h1));
                unsigned short h2 = bf16h(xi);
                vih[j] = (short)h2; vil[j] = (short)bf16h(xi - bf2f(h2));
                float cb = sqrtf(fmaf(xr, xr, xi * xi));
                unsigned short h3 = bf16h(cb);
                vch[j] = (short)h3; vcl[j] = (short)bf16h(cb - bf2f(h3));
            }
            *(bf16x8*)&smem.comp[0][skf][smf][spl][0] = vxh;
            *(bf16x8*)&smem.comp[1][skf][smf][spl][0] = vxl;
            *(bf16x8*)&smem.comp[2][skf][smf][spl][0] = vih;
            *(bf16x8*)&smem.comp[3][skf][smf][spl][0] = vil;
            *(bf16x8*)&smem.comp[4][skf][smf][spl][0] = vch;
            *(bf16x8*)&smem.comp[5][skf][smf][spl][0] = vcl;
        }
        __syncthreads();
        if (db < 31) {   // prefetch next d-block during compute
            const float4* xp = (const float4*)(x2 + (size_t)(m0 + srow) * DIMC
                                               + (db + 1) * 64 + sdg * 8);
            #pragma unroll
            for (int i = 0; i < 4; ++i) q[i] = xp[i];
        }
        const int KTb = db * 2;
        #pragma unroll
        for (int kf = 0; kf < 2; ++kf) {
            bf16x8 ah[4], al[4];
            // ---- xr stream vs W1[ktile = KTb+kf] ----
            #pragma unroll
            for (int mf = 0; mf < 4; ++mf) {
                ah[mf] = *(const bf16x8*)&smem.comp[0][kf][mf][lane][0];
                al[mf] = *(const bf16x8*)&smem.comp[1][kf][mf][lane][0];
            }
            {
                size_t base = ((size_t)(KTb + kf) * 24 + wv * 3) * 64 + lane;
                const bf16x8* bh_p = (const bf16x8*)W1h + base;
                const bf16x8* bl_p = (const bf16x8*)W1l + base;
                #pragma unroll
                for (int nf = 0; nf < 3; ++nf) {
                    bf16x8 bh = bh_p[nf * 64], bl = bl_p[nf * 64];
                    #pragma unroll
                    for (int mf = 0; mf < 4; ++mf) {
                        f32x4 c = c1[nf][mf];
                        c = MFMA(ah[mf], bh, c);
                        c = MFMA(ah[mf], bl, c);
                        c = MFMA(al[mf], bh, c);
                        c1[nf][mf] = c;
                    }
                }
            }
            // ---- xi stream vs W1[ktile = 64 + KTb+kf] ----
            #pragma unroll
            for (int mf = 0; mf < 4; ++mf) {
                ah[mf] = *(const bf16x8*)&smem.comp[2][kf][mf][lane][0];
                al[mf] = *(const bf16x8*)&smem.comp[3][kf][mf][lane][0];
            }
            {
                size_t base = ((size_t)(64 + KTb + kf) * 24 + wv * 3) * 64 + lane;
                const bf16x8* bh_p = (const bf16x8*)W1h + base;
                const bf16x8* bl_p = (const bf16x8*)W1l + base;
                #pragma unroll
                for (int nf = 0; nf < 3; ++nf) {
                    bf16x8 bh = bh_p[nf * 64], bl = bl_p[nf * 64];
                    #pragma unroll
                    for (int mf = 0; mf < 4; ++mf) {
                        f32x4 c = c1[nf][mf];
                        c = MFMA(ah[mf], bh, c);
                        c = MFMA(ah[mf], bl, c);
                        c = MFMA(al[mf], bh, c);
                        c1[nf][mf] = c;
                    }
                }
            }
            // ---- cb stream vs W2 ----
            #pragma unroll
            for (int mf = 0; mf < 4; ++mf) {
                ah[mf] = *(const bf16x8*)&smem.comp[4][kf][mf][lane][0];
                al[mf] = *(const bf16x8*)&smem.comp[5][kf][mf][lane][0];
            }
            {
                size_t base = ((size_t)(KTb + kf) * 8 + wv) * 64 + lane;
                bf16x8 bh = ((const bf16x8*)W2h)[base];
                bf16x8 bl = ((const bf16x8*)W2l)[base];
                #pragma unroll
                for (int mf = 0; mf < 4; ++mf) {
                    f32x4 c = c2[mf];
                    c = MFMA(ah[mf], bh, c);
                    c = MFMA(ah[mf], bl, c);
                    c = MFMA(al[mf], bh, c);
                    c2[mf] = c;
                }
            }
        }
    }

    // ---- fused epilogue: 4 passes (one per mf), 16 rows x 512 cols ----
    const int es = tid & 127;
    const int eq = tid >> 7;          // 0..3
    float eAr  = expf(log_A_real[es]);
    float egr  = cosf(log_A_imag[es]);
    float egi  = sinf(log_A_imag[es]);
    float bsum = dt_b[es] + dt_bias[es];
    float pgb  = pg_b[es];
    float4* AB4 = (float4*)ABx;

    #pragma unroll
    for (int mf = 0; mf < 4; ++mf) {
        __syncthreads();   // previous pass (or main loop) done with LDS
        {
            int rb   = (lane >> 4) * 4;            // C-frag rows rb..rb+3
            int colA = wv * 48 + (lane & 15);
            #pragma unroll
            for (int nf = 0; nf < 3; ++nf) {
                f32x4 c = c1[nf][mf];
                #pragma unroll
                for (int r = 0; r < 4; ++r)
                    smem.ep[rb + r][colA + nf * 16] = c[r];
            }
            f32x4 c = c2[mf];
            int colB = 384 + wv * 16 + (lane & 15);
            #pragma unroll
            for (int r = 0; r < 4; ++r)
                smem.ep[rb + r][colB] = c[r];
        }
        __syncthreads();
        #pragma unroll
        for (int i = 0; i < 4; ++i) {
            int rl = eq * 4 + i;
            float zd   = smem.ep[rl][es]       + bsum;
            float abr  = smem.ep[rl][128 + es];
            float abi  = smem.ep[rl][256 + es];
            float zp   = smem.ep[rl][384 + es] + pgb;
            float dt   = fmaxf(zd, 0.f) + log1pf(expf(-fabsf(zd)));
            float amag = expf(-dt * eAr);
            float pr   = 1.f / (1.f + expf(-zp));
            float omp  = 1.f - pr;
            float Ar_  = fmaf(omp, amag * egr, pr);
            float Ai_  = omp * amag * egi;
            float sc   = omp * dt;
            AB4[(size_t)(m0 + mf * 16 + rl) * SC + es] =
                make_float4(Ar_, Ai_, sc * abr, sc * abi);
        }
    }
}

// ---------------------------------------------------------------------------
// Kernel 2a: per-chunk reduce. Grid = B*NC = 1024, block = 128.
// ---------------------------------------------------------------------------
__global__ void scan_reduce(const float* __restrict__ ABx,
                            float* __restrict__ aggAB) {
    int s = threadIdx.x;
    int c = blockIdx.x & (NC-1);
    int b = blockIdx.x >> 8;
    const float4* AB4 = (const float4*)ABx;
    size_t base = ((size_t)(b * LL + c * LCH) * SC + s);
    float4 v = AB4[base];
    float ar = v.x, ai = v.y, br = v.z, bi = v.w;
    #pragma unroll
    for (int t = 1; t < LCH; ++t) {
        float4 u = AB4[base + (size_t)t * SC];
        float nar = ar*u.x - ai*u.y;
        float nai = ar*u.y + ai*u.x;
        float nbr = br*u.x - bi*u.y + u.z;
        float nbi = br*u.y + bi*u.x + u.w;
        ar = nar; ai = nai; br = nbr; bi = nbi;
    }
    ((float4*)aggAB)[(size_t)blockIdx.x * SC + s] = make_float4(ar, ai, br, bi);
}

// ---------------------------------------------------------------------------
// Kernel 2b: exclusive scan of chunk aggregates (spine). 512 threads total.
// ---------------------------------------------------------------------------
__global__ void scan_spine(const float* __restrict__ aggAB,
                           float* __restrict__ preB) {
    int t = threadIdx.x + blockIdx.x * blockDim.x;   // 0..511
    int s = t & 127, b = t >> 7;
    const float4* A4 = (const float4*)aggAB;
    float2* P2 = (float2*)preB;
    float pa_r = 1.f, pa_i = 0.f, pb_r = 0.f, pb_i = 0.f;
    for (int c = 0; c < NC; ++c) {
        size_t idx = (size_t)(b * NC + c) * SC + s;
        P2[idx] = make_float2(pb_r, pb_i);
        float4 a = A4[idx];
        float nar = pa_r*a.x - pa_i*a.y;
        float nai = pa_r*a.y + pa_i*a.x;
        float nbr = pb_r*a.x - pb_i*a.y + a.z;
        float nbi = pb_r*a.y + pb_i*a.x + a.w;
        pa_r = nar; pa_i = nai; pb_r = nbr; pb_i = nbi;
    }
}

// ---------------------------------------------------------------------------
// Kernel 2c: apply prefixes; h written IN-PLACE into ABx .xy (same-thread
// read-then-write, no race; saves the 16 MB hbuf). Grid = B*NC = 1024.
// ---------------------------------------------------------------------------
__global__ void scan_apply(float* __restrict__ ABx,
                           const float* __restrict__ preB,
                           float* __restrict__ d_out) {
    int s = threadIdx.x;
    int c = blockIdx.x & (NC-1);
    int b = blockIdx.x >> 8;
    float4* AB4 = (float4*)ABx;
    float2 hp = ((const float2*)preB)[(size_t)blockIdx.x * SC + s];
    float hr = hp.x, hi = hp.y;
    size_t base = ((size_t)(b * LL + c * LCH) * SC + s);
    #pragma unroll
    for (int t = 0; t < LCH; ++t) {
        size_t idx = base + (size_t)t * SC;
        float4 u = AB4[idx];
        float nr = u.x*hr - u.y*hi + u.z;
        float ni = u.x*hi + u.y*hr + u.w;
        hr = nr; hi = ni;
        ((float2*)&AB4[idx])[0] = make_float2(hr, hi);
    }
    if (c == NC - 1) {
        float2* hl = (float2*)(d_out + (size_t)MM * DIMC * 2);
        hl[b * SC + s] = make_float2(hr, hi);
    }
}

// ---------------------------------------------------------------------------
// Kernel 3: y = h @ (Cr + i Ci) + D*x via split-bf16 MFMA.
// BM=32, LDS 32 KB, launch_bounds(512,6) -> 3 blocks/CU, 24 waves/CU.
// Grid = 4096 (bn = blk&7 XCD-pins the W3 slice; bm = blk>>3).
// 512 thr (8 waves N-split). BM=32, BN=512, K=256 staged once.
// ---------------------------------------------------------------------------
__global__ __launch_bounds__(512, 6) void phase3(
    const float* __restrict__ ABx,     // .xy = (hr, hi) after scan_apply
    const short* __restrict__ W3h, const short* __restrict__ W3l,
    const float* __restrict__ x,
    const float* __restrict__ Dw,
    float* __restrict__ out)
{
    const int tid  = threadIdx.x;
    const int lane = tid & 63;
    const int wv   = tid >> 6;
    const int bn   = blockIdx.x & 7;
    const int bm   = blockIdx.x >> 3;
    const int m0   = bm * 32;

    __shared__ __align__(16) short ldsA[2][8][2][64][8];   // 32 KB

    // stage h: 32 rows x 128 s; thread = (row = tid>>4, sg = tid&15),
    // s-run = sg*8..sg*8+7 -> ktile kfr = sg>>2 (re), kfr+4 (im);
    // lane-slot = (row&15) + 16*(sg&3); mf = row>>4.
    {
        int row = tid >> 4, sg = tid & 15;
        int mf = row >> 4, r15 = row & 15;
        int kfr = sg >> 2, lg = sg & 3;
        int pl = r15 + 16 * lg;
        const float4* hp = (const float4*)ABx + (size_t)(m0 + row) * SC + sg * 8;
        bf16x8 rh, rl, ih, il;
        #pragma unroll
        for (int j = 0; j < 8; ++j) {
            float4 u = hp[j];
            unsigned short h1 = bf16h(u.x);
            rh[j] = (short)h1; rl[j] = (short)bf16h(u.x - bf2f(h1));
            unsigned short h2 = bf16h(u.y);
            ih[j] = (short)h2; il[j] = (short)bf16h(u.y - bf2f(h2));
        }
        *(bf16x8*)&ldsA[0][kfr][mf][pl][0]     = rh;
        *(bf16x8*)&ldsA[1][kfr][mf][pl][0]     = rl;
        *(bf16x8*)&ldsA[0][kfr + 4][mf][pl][0] = ih;
        *(bf16x8*)&ldsA[1][kfr + 4][mf][pl][0] = il;
    }
    __syncthreads();

    f32x4 c[4][2];   // [nf_local][mf]
    #pragma unroll
    for (int n = 0; n < 4; ++n)
        #pragma unroll
        for (int m = 0; m < 2; ++m) c[n][m] = (f32x4){0.f,0.f,0.f,0.f};

    #pragma unroll
    for (int kf = 0; kf < 8; ++kf) {
        bf16x8 ah[2], al[2];
        #pragma unroll
        for (int mf = 0; mf < 2; ++mf) {
            ah[mf] = *(const bf16x8*)&ldsA[0][kf][mf][lane][0];
            al[mf] = *(const bf16x8*)&ldsA[1][kf][mf][lane][0];
        }
        size_t base = ((size_t)kf * 256 + bn * 32 + wv * 4) * 64 + lane;
        const bf16x8* bh_p = (const bf16x8*)W3h + base;
        const bf16x8* bl_p = (const bf16x8*)W3l + base;
        #pragma unroll
        for (int nf = 0; nf < 4; ++nf) {
            bf16x8 bh = bh_p[nf * 64], bl = bl_p[nf * 64];
            #pragma unroll
            for (int mf = 0; mf < 2; ++mf) {
                f32x4 cc = c[nf][mf];
                cc = MFMA(ah[mf], bh, cc);
                cc = MFMA(ah[mf], bl, cc);
                cc = MFMA(al[mf], bh, cc);
                c[nf][mf] = cc;
            }
        }
    }

    // epilogue: + D*x, coalesced stores (n = d*2+comp is the flat out index)
    const float2* x2  = (const float2*)x;
    const float2* Dw2 = (const float2*)Dw;
    #pragma unroll
    for (int nf = 0; nf < 4; ++nf) {
        int n = bn * 512 + wv * 64 + nf * 16 + (lane & 15);
        int d = n >> 1, comp = n & 1;
        float2 dw = Dw2[d];
        #pragma unroll
        for (int mf = 0; mf < 2; ++mf) {
            f32x4 cc = c[nf][mf];
            int mbase = m0 + mf * 16 + (lane >> 4) * 4;
            #pragma unroll
            for (int r = 0; r < 4; ++r) {
                int m = mbase + r;
                float2 xv = x2[(size_t)m * DIMC + d];
                float val = cc[r] + (comp ? fmaf(dw.x, xv.y,  dw.y * xv.x)
                                          : fmaf(dw.x, xv.x, -dw.y * xv.y));
                out[(size_t)m * 4096 + n] = val;
            }
        }
    }
}

// ---------------------------------------------------------------------------
extern "C" void kernel_launch(void* const* d_in, const int* in_sizes, int n_in,
                              void* d_out, int out_size, void* d_ws, size_t ws_size,
                              hipStream_t stream) {
    const float* x          = (const float*)d_in[0];
    const float* log_A_real = (const float*)d_in[1];
    const float* log_A_imag = (const float*)d_in[2];
    const float* Dw         = (const float*)d_in[3];
    const float* dt_w       = (const float*)d_in[4];
    const float* dt_b       = (const float*)d_in[5];
    const float* dt_bias    = (const float*)d_in[6];
    const float* Br         = (const float*)d_in[7];
    const float* Bi         = (const float*)d_in[8];
    const float* Cr         = (const float*)d_in[9];
    const float* Ci         = (const float*)d_in[10];
    const float* pg_w       = (const float*)d_in[11];
    const float* pg_b       = (const float*)d_in[12];

    float* out = (float*)d_out;
    float* ws  = (float*)d_ws;

    // Workspace (floats): total 12,058,624 = 48.2 MB
    short* W1h = (short*)ws;                          // 1,572,864 shorts
    short* W1l = W1h + (size_t)W1_SLOTS * 64 * 8;     // 1,572,864
    short* W2h = W1l + (size_t)W1_SLOTS * 64 * 8;     //   262,144
    short* W2l = W2h + (size_t)W2_SLOTS * 64 * 8;     //   262,144
    float* aggAB = ws + 1835008;                      //   524,288 floats
    float* preB  = aggAB + (size_t)BB * NC * SC * 4;  //   262,144
    float* ABx   = ws + 2621440;                      // 8,388,608
    short* W3h   = (short*)(ws + 2621440 + 8388608);  // 1,048,576 shorts
    short* W3l   = W3h + (size_t)W3_SLOTS * 64 * 8;   // 1,048,576

    hipLaunchKernelGGL(prep_w, dim3((W1_SLOTS+W2_SLOTS+W3_SLOTS)*64/256), dim3(256), 0, stream,
                       dt_w, Br, Bi, pg_w, Cr, Ci, W1h, W1l, W2h, W2l, W3h, W3l);
    hipLaunchKernelGGL(phase1, dim3(MM/64), dim3(512), 0, stream,
                       x, W1h, W1l, W2h, W2l, log_A_real, log_A_imag,
                       dt_b, dt_bias, pg_b, ABx);
    hipLaunchKernelGGL(scan_reduce, dim3(BB*NC), dim3(128), 0, stream,
                       ABx, aggAB);
    hipLaunchKernelGGL(scan_spine, dim3(2), dim3(256), 0, stream,
                       aggAB, preB);
    hipLaunchKernelGGL(scan_apply, dim3(BB*NC), dim3(128), 0, stream,
                       ABx, preB, out);
    hipLaunchKernelGGL(phase3, dim3(4096), dim3(512), 0, stream,
                       ABx, W3h, W3l, x, Dw, out);
}